// Round 16
// baseline (161.916 us; speedup 1.0000x reference)
//
#include <hip/hip_runtime.h>

// TFLite STFT as bf16 MFMA GEMM. Output: real part only,
// out[(b*2397+f)*401+k], 15,379,152 floats.
// Round 16: within-probe A/B. v1 = exact R12 kernel (69.7us full-grid champ)
// on b<8; v2 = same + full ks-loop unroll (register software-pipelining) on
// b>=8. Separate template instantiations -> separate rocprof rows.
// R13 (64f tile) and R15 (LDS-B + barrier/ks) both LOST to R12; all pipes
// <20% busy => per-wave load->MFMA dependency stalls are the residual theory.

#define NB      16
#define NT      480000
#define FLEN    800
#define STEP    200
#define NFRAMES 2397
#define NBINS   401

#define NKT     28                      // k-tiles of 16 bins (448 total)
#define NKS     25                      // K-chunks of 32 (800/32)
#define GX      7                       // k-column blocks (64 bins each)
#define GY      19                      // frame blocks (128 frames each)
#define SIG_OFF (1u << 20)              // sig bf16 at +1MB in ws
#define WS_NEED (SIG_OFF + (size_t)NB * NT * 2)

typedef __bf16 bf16x8 __attribute__((ext_vector_type(8)));
typedef __bf16 bf16x4 __attribute__((ext_vector_type(4)));
typedef float  f32x4  __attribute__((ext_vector_type(4)));

// ---- fused prep: W frag-build (first BUILD_BLOCKS) + sig fp32->bf16 ----
#define BUILD_THREADS (NKS * NKT * 64)                // 44800
#define BUILD_BLOCKS  ((BUILD_THREADS + 255) / 256)   // 175
#define CONV_ITEMS    ((size_t)NB * NT / 4)           // 1.92M float4s
#define CONV_BLOCKS   ((int)((CONV_ITEMS + 255) / 256))

__global__ __launch_bounds__(256)
void prep_kernel(const float* __restrict__ sig, const float* __restrict__ win,
                 __bf16* __restrict__ w, __bf16* __restrict__ sigb) {
    if (blockIdx.x < BUILD_BLOCKS) {
        // W in B-fragment-linear layout: frag = ks*NKT + kt;
        // lane: col(bin) = kt*16 + (lane&15); elem j: l = ks*32 + (lane>>4)*8 + j.
        int t = blockIdx.x * 256 + threadIdx.x;
        if (t >= BUILD_THREADS) return;
        int lane = t & 63, frag = t >> 6;
        int kt = frag % NKT, ks = frag / NKT;
        int bin = kt * 16 + (lane & 15);
        int lbase = ks * 32 + (lane >> 4) * 8;
        bf16x8 o;
        #pragma unroll
        for (int j = 0; j < 8; ++j) {
            int l = lbase + j;
            int m = (bin * l) % FLEN;                 // exact reduction
            float c = cosf((float)m * -0.00785398163397448279f) * win[l];
            o[j] = (__bf16)c;
        }
        ((bf16x8*)w)[t] = o;
    } else {
        size_t i = (size_t)(blockIdx.x - BUILD_BLOCKS) * 256 + threadIdx.x;
        if (i >= CONV_ITEMS) return;
        float4 v = ((const float4*)sig)[i];
        bf16x4 o;
        o[0] = (__bf16)v.x; o[1] = (__bf16)v.y; o[2] = (__bf16)v.z; o[3] = (__bf16)v.w;
        ((bf16x4*)sigb)[i] = o;
    }
}

// ---- main: bf16 MFMA GEMM, 4 waves x (32f x 64k), block 128f x 64k ----
// NBZ batches starting at BOFF; UNROLL toggles full ks-loop unroll.
template <int NBZ, int BOFF, bool UNROLL>
__global__ __launch_bounds__(256)
void stft_mfma(const __bf16* __restrict__ sigb,
               const __bf16* __restrict__ w,
               float* __restrict__ out) {
    constexpr int NWGV = GX * GY * NBZ;     // 1064 for NBZ=8
    constexpr int PXC  = NWGV / 8;          // 133: bijective XCD swizzle
    const int D = blockIdx.x + GX * (blockIdx.y + GY * blockIdx.z);
    const int P = (D % 8) * PXC + (D / 8);
    const int x = P % GX;
    const int y = (P / GX) % GY;
    const int b = BOFF + P / (GX * GY);

    const int lane = threadIdx.x & 63;
    const int wid  = threadIdx.x >> 6;   // 0..3
    const int f0   = y * 128 + wid * 32;
    const int kt0  = x * 4;
    const int r    = lane & 15;      // A row / C col within 16-tile
    const int h    = lane >> 4;      // K-half group 0..3

    const __bf16* sb = sigb + (size_t)b * NT;
    const bf16x8* wf = (const bf16x8*)w;

    const bf16x8* ap0; const bf16x8* ap1;
    {
        int r0 = f0 + r;      if (r0 > NFRAMES - 1) r0 = NFRAMES - 1;
        int r1 = f0 + 16 + r; if (r1 > NFRAMES - 1) r1 = NFRAMES - 1;
        ap0 = (const bf16x8*)(sb + (size_t)r0 * STEP) + h;   // 16B aligned
        ap1 = (const bf16x8*)(sb + (size_t)r1 * STEP) + h;
    }

    f32x4 acc[2][4];
    #pragma unroll
    for (int m = 0; m < 2; ++m)
        #pragma unroll
        for (int n = 0; n < 4; ++n)
            acc[m][n] = (f32x4){0.f, 0.f, 0.f, 0.f};

    #define KS_BODY(KS)                                                              \
        {                                                                            \
            bf16x8 a0 = ap0[(KS) * 4];                                               \
            bf16x8 a1 = ap1[(KS) * 4];                                               \
            bf16x8 b0 = wf[(size_t)((KS) * NKT + kt0 + 0) * 64 + lane];              \
            bf16x8 b1 = wf[(size_t)((KS) * NKT + kt0 + 1) * 64 + lane];              \
            bf16x8 b2 = wf[(size_t)((KS) * NKT + kt0 + 2) * 64 + lane];              \
            bf16x8 b3 = wf[(size_t)((KS) * NKT + kt0 + 3) * 64 + lane];              \
            acc[0][0] = __builtin_amdgcn_mfma_f32_16x16x32_bf16(a0, b0, acc[0][0], 0, 0, 0); \
            acc[0][1] = __builtin_amdgcn_mfma_f32_16x16x32_bf16(a0, b1, acc[0][1], 0, 0, 0); \
            acc[0][2] = __builtin_amdgcn_mfma_f32_16x16x32_bf16(a0, b2, acc[0][2], 0, 0, 0); \
            acc[0][3] = __builtin_amdgcn_mfma_f32_16x16x32_bf16(a0, b3, acc[0][3], 0, 0, 0); \
            acc[1][0] = __builtin_amdgcn_mfma_f32_16x16x32_bf16(a1, b0, acc[1][0], 0, 0, 0); \
            acc[1][1] = __builtin_amdgcn_mfma_f32_16x16x32_bf16(a1, b1, acc[1][1], 0, 0, 0); \
            acc[1][2] = __builtin_amdgcn_mfma_f32_16x16x32_bf16(a1, b2, acc[1][2], 0, 0, 0); \
            acc[1][3] = __builtin_amdgcn_mfma_f32_16x16x32_bf16(a1, b3, acc[1][3], 0, 0, 0); \
        }

    if constexpr (UNROLL) {
        #pragma unroll
        for (int ks = 0; ks < NKS; ++ks) KS_BODY(ks)
    } else {
        for (int ks = 0; ks < NKS; ++ks) KS_BODY(ks)
    }
    #undef KS_BODY

    // C/D layout: col = lane&15 (bin), row = (lane>>4)*4 + reg (frame)
    const size_t ob = (size_t)b * NFRAMES;
    #pragma unroll
    for (int m = 0; m < 2; ++m) {
        int fbase = f0 + m * 16 + h * 4;
        #pragma unroll
        for (int n = 0; n < 4; ++n) {
            int k = x * 64 + n * 16 + r;
            if (k < NBINS) {
                #pragma unroll
                for (int reg = 0; reg < 4; ++reg) {
                    int f = fbase + reg;
                    if (f < NFRAMES)
                        out[(ob + f) * NBINS + k] = acc[m][n][reg];
                }
            }
        }
    }
}

// ---- fp32 fallback (proven round 10): used only if ws too small ----
#define BFT 32
#define BKT 32
#define LCH 100
#define LPAD 108
__global__ __launch_bounds__(256)
void stft_f32_kernel(const float* __restrict__ sig, const float* __restrict__ win,
                     float* __restrict__ out) {
    __shared__ float s_sig[(BFT - 1) * STEP + LCH];
    __shared__ float s_cw[BKT][LPAD];
    const int tid = threadIdx.x;
    const int k0 = blockIdx.x * BKT, f0 = blockIdx.y * BFT, b = blockIdx.z;
    const int kk = tid & 15, ff = tid >> 4;
    float r00 = 0.f, r01 = 0.f, r10 = 0.f, r11 = 0.f;
    const float* sigb = sig + (size_t)b * NT;
    for (int l0 = 0; l0 < FLEN; l0 += LCH) {
        for (int i = tid; i < (BFT - 1) * STEP + LCH; i += 256) {
            int gs = f0 * STEP + l0 + i;
            s_sig[i] = (gs < NT) ? sigb[gs] : 0.0f;
        }
        for (int i = tid; i < BKT * LCH; i += 256) {
            int kx = i / LCH, dl = i - kx * LCH, k = k0 + kx, l = l0 + dl;
            float c = 0.f;
            if (k < NBINS) {
                int m = (k * l) % FLEN;
                c = __cosf((float)m * -0.00785398163397448279f) * win[l];
            }
            s_cw[kx][dl] = c;
        }
        __syncthreads();
        for (int dl = 0; dl < LCH; dl += 4) {
            float4 a0 = *(const float4*)&s_sig[ff * STEP + dl];
            float4 a1 = *(const float4*)&s_sig[(ff + 16) * STEP + dl];
            float4 c0 = *(const float4*)&s_cw[kk][dl];
            float4 c1 = *(const float4*)&s_cw[kk + 16][dl];
            r00 = fmaf(a0.x, c0.x, r00); r00 = fmaf(a0.y, c0.y, r00);
            r00 = fmaf(a0.z, c0.z, r00); r00 = fmaf(a0.w, c0.w, r00);
            r01 = fmaf(a0.x, c1.x, r01); r01 = fmaf(a0.y, c1.y, r01);
            r01 = fmaf(a0.z, c1.z, r01); r01 = fmaf(a0.w, c1.w, r01);
            r10 = fmaf(a1.x, c0.x, r10); r10 = fmaf(a1.y, c0.y, r10);
            r10 = fmaf(a1.z, c0.z, r10); r10 = fmaf(a1.w, c0.w, r10);
            r11 = fmaf(a1.x, c1.x, r11); r11 = fmaf(a1.y, c1.y, r11);
            r11 = fmaf(a1.z, c1.z, r11); r11 = fmaf(a1.w, c1.w, r11);
        }
        __syncthreads();
    }
    const size_t ob = (size_t)b * NFRAMES;
    { int f = f0 + ff,      k = k0 + kk;      if (f < NFRAMES && k < NBINS) out[(ob + f) * NBINS + k] = r00; }
    { int f = f0 + ff,      k = k0 + kk + 16; if (f < NFRAMES && k < NBINS) out[(ob + f) * NBINS + k] = r01; }
    { int f = f0 + ff + 16, k = k0 + kk;      if (f < NFRAMES && k < NBINS) out[(ob + f) * NBINS + k] = r10; }
    { int f = f0 + ff + 16, k = k0 + kk + 16; if (f < NFRAMES && k < NBINS) out[(ob + f) * NBINS + k] = r11; }
}

extern "C" void kernel_launch(void* const* d_in, const int* in_sizes, int n_in,
                              void* d_out, int out_size, void* d_ws, size_t ws_size,
                              hipStream_t stream) {
    const float* sig = (const float*)d_in[0];
    const float* win = (const float*)d_in[1];
    float* out = (float*)d_out;

    if (ws_size >= WS_NEED) {
        __bf16* wfr    = (__bf16*)d_ws;
        __bf16* sigb16 = (__bf16*)((char*)d_ws + SIG_OFF);
        prep_kernel<<<dim3(BUILD_BLOCKS + CONV_BLOCKS), dim3(256), 0, stream>>>(sig, win, wfr, sigb16);
        dim3 ghalf(GX, GY, 8);   // 7 x 19 x 8 = 1064 blocks each
        stft_mfma<8, 0, false><<<ghalf, dim3(256), 0, stream>>>(sigb16, wfr, out);  // v1: R12 control
        stft_mfma<8, 8, true ><<<ghalf, dim3(256), 0, stream>>>(sigb16, wfr, out);  // v2: full unroll
    } else {
        dim3 grid((NBINS + BKT - 1) / BKT, (NFRAMES + BFT - 1) / BFT, NB);
        stft_f32_kernel<<<grid, dim3(256), 0, stream>>>(sig, win, out);
    }
}